// Round 4
// baseline (699.634 us; speedup 1.0000x reference)
//
#include <hip/hip_runtime.h>

// penalty = (1/10) * sum_j trace(cov(class j)), unbiased (n-1).
// trace_j = (Sum_{i in j} ||x_i||^2 - Sum_d S_{j,d}^2 / n_j) / (n_j - 1)
// Memory-bound target: read 512MB of x exactly once (~85us at 6.3 TB/s).
//
// v3: one ROW per 64-lane WAVE (float2/lane = 512B/row, fully coalesced).
// t[row] is wave-uniform -> readfirstlane + scalar branch chain: only the
// taken class's 4 adds execute (SALU handles dispatch, VALU stays ~idle).
// 4-row unroll: 2KB in flight per wave; x16 waves/CU = 32KB >> 9KB needed
// to cover ~900cy HBM latency. __launch_bounds__(256,4) -> VGPR<=128.
// SALU budget: ~80 ops/wave-iter, 16 waves/CU over ~3200cy window = ~40%.

#define NCLS 10
#define DFEAT 128
#define NB 1024                  // blocks for the main pass (4 per CU)
#define BLK 256                  // threads per block = 4 waves
#define WPB (BLK / 64)           // waves per block
#define NWAVE (NB * WPB)         // 4096 global waves
#define COLS (NCLS * 130)        // per class: 128 sums + sumsq + count -> 1300

struct Acc {
    float2 s[NCLS];
    float sq[NCLS];
    float cn[NCLS];
};

__device__ __forceinline__ void acc_row(Acc& a, float2 v, int scls) {
    float d2 = fmaf(v.y, v.y, v.x * v.x);
#pragma unroll
    for (int c = 0; c < NCLS; ++c) {
        if (scls == c) {  // scls is SGPR -> s_cmp + s_cbranch, one body taken
            a.s[c].x += v.x;
            a.s[c].y += v.y;
            a.sq[c] += d2;
            a.cn[c] += 1.0f;  // 64 lanes each add 1 -> totals are 64*n_j
        }
    }
}

__global__ __launch_bounds__(BLK, 4) void k_partial(const float* __restrict__ x,
                                                    const int* __restrict__ t,
                                                    float* __restrict__ partial,
                                                    int N) {
    const int tid = threadIdx.x;
    const int lane = tid & 63;
    const int wave = blockIdx.x * WPB + (tid >> 6);

    Acc a;
#pragma unroll
    for (int c = 0; c < NCLS; ++c) {
        a.s[c] = make_float2(0.f, 0.f);
        a.sq[c] = 0.f;
        a.cn[c] = 0.f;
    }

    // per-wave base pointer; per-row step is a constant element offset
    const float2* __restrict__ p0 = (const float2*)x + (size_t)wave * 64 + lane;
    const size_t rstep = (size_t)NWAVE * 64;  // float2 elements per row-step

    int row = wave;
    const float2* p = p0;
    for (; row + 3 * NWAVE < N; row += 4 * NWAVE, p += 4 * rstep) {
        int c0 = t[row];
        int c1 = t[row + NWAVE];
        int c2 = t[row + 2 * NWAVE];
        int c3 = t[row + 3 * NWAVE];
        float2 v0 = p[0];
        float2 v1 = p[rstep];
        float2 v2 = p[2 * rstep];
        float2 v3 = p[3 * rstep];
        acc_row(a, v0, __builtin_amdgcn_readfirstlane(c0));
        acc_row(a, v1, __builtin_amdgcn_readfirstlane(c1));
        acc_row(a, v2, __builtin_amdgcn_readfirstlane(c2));
        acc_row(a, v3, __builtin_amdgcn_readfirstlane(c3));
    }
    for (; row < N; row += NWAVE, p += rstep) {
        int c0 = t[row];
        float2 v0 = p[0];
        acc_row(a, v0, __builtin_amdgcn_readfirstlane(c0));
    }

    // ---- block-level reduction into LDS ----
    // lane holds features d = 2*lane, 2*lane+1; 4 waves/block share addresses.
    __shared__ float smem[COLS];
    for (int i = tid; i < COLS; i += BLK) smem[i] = 0.0f;
    __syncthreads();

#pragma unroll
    for (int c = 0; c < NCLS; ++c) {
        atomicAdd(&smem[c * 130 + lane * 2 + 0], a.s[c].x);
        atomicAdd(&smem[c * 130 + lane * 2 + 1], a.s[c].y);
        // sq/cn: reduce across the wave first, then 1 atomic per wave
        float q = a.sq[c], n = a.cn[c];
#pragma unroll
        for (int off = 32; off > 0; off >>= 1) {
            q += __shfl_down(q, off, 64);
            n += __shfl_down(n, off, 64);
        }
        if (lane == 0) {
            atomicAdd(&smem[c * 130 + 128], q);
            atomicAdd(&smem[c * 130 + 129], n);
        }
    }
    __syncthreads();

    // column-major partials: partial[col][block] for coalesced stage-2 reads
    for (int i = tid; i < COLS; i += BLK)
        partial[(size_t)i * NB + blockIdx.x] = smem[i];
}

__global__ __launch_bounds__(64) void k_colsum(const float* __restrict__ partial,
                                               float* __restrict__ totals) {
    const int col = blockIdx.x;
    const float* p = partial + (size_t)col * NB;
    float v = 0.f;
    for (int i = threadIdx.x; i < NB; i += 64) v += p[i];
#pragma unroll
    for (int off = 32; off > 0; off >>= 1) v += __shfl_down(v, off, 64);
    if (threadIdx.x == 0) totals[col] = v;
}

__global__ __launch_bounds__(64) void k_final(const float* __restrict__ totals,
                                              float* __restrict__ out) {
    const int lane = threadIdx.x;
    float tr = 0.0f;
    if (lane < NCLS) {
        const float* b = totals + lane * 130;
        float ss = 0.f;
        for (int d = 0; d < DFEAT; ++d) {
            float u = b[d];
            ss += u * u;
        }
        float S2 = b[128];
        float n = b[129] * (1.0f / 64.0f);  // undo the x64 lane replication
        tr = (S2 - ss / n) / (n - 1.0f);
    }
#pragma unroll
    for (int off = 32; off > 0; off >>= 1) tr += __shfl_down(tr, off, 64);
    if (lane == 0) out[0] = tr / (float)NCLS;
}

extern "C" void kernel_launch(void* const* d_in, const int* in_sizes, int n_in,
                              void* d_out, int out_size, void* d_ws, size_t ws_size,
                              hipStream_t stream) {
    const float* x = (const float*)d_in[0];
    const int* t = (const int*)d_in[1];
    const int N = in_sizes[1];  // t has N elements; x has N*128

    float* partial = (float*)d_ws;                       // COLS * NB floats
    float* totals = partial + (size_t)COLS * NB;         // COLS floats
    float* out = (float*)d_out;

    k_partial<<<NB, BLK, 0, stream>>>(x, t, partial, N);
    k_colsum<<<COLS, 64, 0, stream>>>(partial, totals);
    k_final<<<1, 64, 0, stream>>>(totals, out);
}